// Round 9
// baseline (1078.399 us; speedup 1.0000x reference)
//
#include <hip/hip_runtime.h>
#include <hip/hip_bf16.h>
#include <stdint.h>

#define DI __device__ __forceinline__

typedef __attribute__((ext_vector_type(8))) __bf16 bf16x8;
typedef __attribute__((ext_vector_type(8))) unsigned short u16x8;
typedef __attribute__((ext_vector_type(4))) unsigned short u16x4;
typedef __attribute__((ext_vector_type(4))) float f32x4;

typedef __attribute__((address_space(1))) const unsigned int* gp1;
typedef __attribute__((address_space(3))) unsigned int* lp3;

static constexpr int Mdim = 8192;   // B*S
static constexpr int Kdim = 4096;   // D
static constexpr int Ndim = 16384;  // F
static constexpr int NT = Kdim / 64;     // 64 K-tiles of BK=64
static constexpr int ROWB = Kdim * 2;    // 8192 B per bf16 row (A and Bt)

// LDS map (160 KiB total, 1 block/CU):
//   A double buffer: [0, 32768), [32768, 65536)      (each 256 rows x 64 cols bf16)
//   B triple buffer: [65536, 98304), [98304, 131072), [131072, 163840)
static constexpr int B0OFF = 65536;

DI unsigned short f2bf(float f) {
  union { float f; unsigned int u; } v;
  v.f = f;
  unsigned int u = v.u;
  unsigned int r = (u + 0x7fffu + ((u >> 16) & 1u)) >> 16;  // RNE
  return (unsigned short)r;
}

DI void gload_lds16(const void* g, void* l) {
  // width=16 -> global_load_lds_dwordx4; LDS dest = wave-uniform base + lane*16
  __builtin_amdgcn_global_load_lds((gp1)g, (lp3)l, 16, 0, 0);
}

DI bf16x8 ldfrag(const char* p) {
  return __builtin_bit_cast(bf16x8, *reinterpret_cast<const u16x8*>(p));
}

#define MFMA_(A_, B_, ACC_) \
  ACC_ = __builtin_amdgcn_mfma_f32_16x16x32_bf16(A_, B_, ACC_, 0, 0, 0)

// 16-MFMA cluster: two m-rows (M0_,M1_) x 4 n-cols x K=64.
// NO setprio: in a free-slip (1-barrier/tile) schedule, prio-1 MFMA waves
// starve the SIMD-mate's ds_read issue (m190: setprio negative off-lockstep).
#define PHASE16(A0_, A1_, A2_, A3_, M0_, M1_)                         \
  MFMA_(A0_, b00, acc[M0_][0]); MFMA_(A1_, b01, acc[M0_][0]);         \
  MFMA_(A2_, b00, acc[M1_][0]); MFMA_(A3_, b01, acc[M1_][0]);         \
  MFMA_(A0_, b10, acc[M0_][1]); MFMA_(A1_, b11, acc[M0_][1]);         \
  MFMA_(A2_, b10, acc[M1_][1]); MFMA_(A3_, b11, acc[M1_][1]);         \
  MFMA_(A0_, b20, acc[M0_][2]); MFMA_(A1_, b21, acc[M0_][2]);         \
  MFMA_(A2_, b20, acc[M1_][2]); MFMA_(A3_, b21, acc[M1_][2]);         \
  MFMA_(A0_, b30, acc[M0_][3]); MFMA_(A1_, b31, acc[M0_][3]);         \
  MFMA_(A2_, b30, acc[M1_][3]); MFMA_(A3_, b31, acc[M1_][3])

// load all 8 B frags of a tile from B region R_
#define LDB8(R_)                                            \
  b00 = ldfrag(R_ + boffR + 0 * 2048 + kofs0);              \
  b01 = ldfrag(R_ + boffR + 0 * 2048 + kofs1);              \
  b10 = ldfrag(R_ + boffR + 1 * 2048 + kofs0);              \
  b11 = ldfrag(R_ + boffR + 1 * 2048 + kofs1);              \
  b20 = ldfrag(R_ + boffR + 2 * 2048 + kofs0);              \
  b21 = ldfrag(R_ + boffR + 2 * 2048 + kofs1);              \
  b30 = ldfrag(R_ + boffR + 3 * 2048 + kofs0);              \
  b31 = ldfrag(R_ + boffR + 3 * 2048 + kofs1)

// load one A frag pair (rows-of-16 P_ and P_+1) from A buffer
#define LDA4(D0_, D1_, D2_, D3_, BUF_, P_)                  \
  D0_ = ldfrag(BUF_ + aoff + (P_) * 2048 + kofs0);          \
  D1_ = ldfrag(BUF_ + aoff + (P_) * 2048 + kofs1);          \
  D2_ = ldfrag(BUF_ + aoff + (P_ + 1) * 2048 + kofs0);      \
  D3_ = ldfrag(BUF_ + aoff + (P_ + 1) * 2048 + kofs1)

// Stage one 128-row x 64-col bf16 half-tile (16 KiB) into a linear LDS region.
// Global source is pre-swizzled per-lane so that a swizzled READ
// (byte ^= (row&7)<<4) sees the correct data (both-sides-or-neither rule).
DI void stage_half(const char* g, int row0, int Tk, char* region, int wave, int lane) {
  const int r = wave * 16 + (lane >> 3);
  const int colx = (((lane & 7) ^ ((lane >> 3) & 7)) << 4);
  const char* src = g + (size_t)(row0 + r) * ROWB + Tk * 128 + colx;
  char* dst = region + wave * 2048;  // wave-uniform
  gload_lds16(src, dst);
  gload_lds16(src + (size_t)8 * ROWB, dst + 1024);
}

// ---------------- pre-pass: A fp32 -> bf16 ----------------
__global__ void k_convertA(const float* __restrict__ in,
                           unsigned short* __restrict__ out, int n8) {
  int stride = gridDim.x * blockDim.x;
  for (int i = blockIdx.x * blockDim.x + threadIdx.x; i < n8; i += stride) {
    const float4* p = reinterpret_cast<const float4*>(in) + (size_t)i * 2;
    float4 a = p[0], b = p[1];
    u16x8 o;
    o[0] = f2bf(a.x); o[1] = f2bf(a.y); o[2] = f2bf(a.z); o[3] = f2bf(a.w);
    o[4] = f2bf(b.x); o[5] = f2bf(b.y); o[6] = f2bf(b.z); o[7] = f2bf(b.w);
    reinterpret_cast<u16x8*>(out)[i] = o;
  }
}

// -------- pre-pass: B (K,N) fp32 -> Bt (N,K) bf16 --------
__global__ void k_transB(const float* __restrict__ B,
                         unsigned short* __restrict__ Bt) {
  __shared__ unsigned short lds[64][68];
  const int n0 = blockIdx.x * 64;
  const int k0 = blockIdx.y * 64;
  const int tid = threadIdx.x;
  const int rr = tid >> 4;
  const int cc = tid & 15;
#pragma unroll
  for (int i = 0; i < 4; ++i) {
    int r = rr + i * 16;
    float4 v = *reinterpret_cast<const float4*>(B + (size_t)(k0 + r) * Ndim + n0 + cc * 4);
    u16x4 o;
    o[0] = f2bf(v.x); o[1] = f2bf(v.y); o[2] = f2bf(v.z); o[3] = f2bf(v.w);
    *reinterpret_cast<u16x4*>(&lds[r][cc * 4]) = o;
  }
  __syncthreads();
#pragma unroll
  for (int i = 0; i < 4; ++i) {
    int n = rr + i * 16;
    u16x4 o;
    o[0] = lds[cc * 4 + 0][n];
    o[1] = lds[cc * 4 + 1][n];
    o[2] = lds[cc * 4 + 2][n];
    o[3] = lds[cc * 4 + 3][n];
    *reinterpret_cast<u16x4*>(Bt + (size_t)(n0 + n) * Kdim + k0 + cc * 4) = o;
  }
}

// ---------------- 256x256 GEMM, 1-barrier/tile, B triple-buffered ----------------
// A(M,K) bf16 x Bt(N,K) bf16 -> C(M,N) fp32 + bias
// 512 threads = 8 waves (2M x 4N); per-wave output 128x64 of 16x16x32 MFMA.
// Block->tile map: per-XCD 8m x 4n co-resident patches; chunk order iterates
// m-slab INNER so each B-half stays L3-resident across 4 consecutive chunks.
__global__ __launch_bounds__(512, 2) void k_gemm8(const unsigned short* __restrict__ A,
                                                  const unsigned short* __restrict__ Bt,
                                                  const float* __restrict__ bias,
                                                  float* __restrict__ C) {
  extern __shared__ char sm[];
  const int tid = threadIdx.x;
  const int wave = tid >> 6, lane = tid & 63;
  const int wm = wave >> 2, wn = wave & 3;
  const int lrow = lane & 15, khi = lane >> 4;

  int m0, n0;
  {
    // 2048 blocks = 8 XCDs x 8 chunks x 32 blocks.
    // chunk c: m-slab = c&3 (inner), n-half = c>>2 (outer) -> B-half reused
    // across 4 consecutive chunks (L3-resident), A-slab shared across XCDs.
    const int bid = blockIdx.x;
    const int xcd = bid & 7;
    const int local = bid >> 3;      // 0..255
    const int c = local >> 5;        // 0..7
    const int i = local & 31;        // 0..31
    const int mt = (c & 3) * 8 + (i & 7);                  // 0..31
    const int nt = xcd * 8 + (c >> 2) * 4 + (i >> 3);      // 0..63
    m0 = mt * 256;
    n0 = nt * 256;
  }

  const char* Ag = (const char*)A;
  const char* Bg = (const char*)Bt;

  // swizzled within-row k-offsets for the two K=32 steps of a BK=64 tile
  const int kofs0 = (khi * 16) ^ ((lane & 7) << 4);
  const int kofs1 = (64 + khi * 16) ^ ((lane & 7) << 4);
  const int aoff  = (wm * 128 + lrow) * 128;   // A frag row base (bytes, within A buf)
  const int boffR = (wn * 64 + lrow) * 128;    // B frag row base (bytes, within B region)

  f32x4 acc[8][4];
#pragma unroll
  for (int i = 0; i < 8; ++i)
#pragma unroll
    for (int j = 0; j < 4; ++j) acc[i][j] = f32x4{0.f, 0.f, 0.f, 0.f};

  // ---- prologue: A(0), B(0), B(1); leave B(1) (4 loads) in flight
  stage_half(Ag, m0,       0, sm + 0,              wave, lane);
  stage_half(Ag, m0 + 128, 0, sm + 16384,          wave, lane);
  stage_half(Bg, n0,       0, sm + B0OFF,          wave, lane);
  stage_half(Bg, n0 + 128, 0, sm + B0OFF + 16384,  wave, lane);
  stage_half(Bg, n0,       1, sm + B0OFF + 32768,  wave, lane);
  stage_half(Bg, n0 + 128, 1, sm + B0OFF + 49152,  wave, lane);
  asm volatile("s_waitcnt vmcnt(4)" ::: "memory");
  __builtin_amdgcn_sched_barrier(0);
  __builtin_amdgcn_s_barrier();

  // rotating B region pointers: BR = read region (T%3), BS = stage region ((T+2)%3)
  char* BR = sm + B0OFF;
  char* BS = sm + B0OFF + 2 * 32768;

  // ---- steady tiles: T in [0, NT-3]; stages A(T+1), B(T+2); ONE barrier/tile
  for (int T = 0; T < NT - 2; ++T) {
    char* bufA  = sm + (T & 1) * 32768;
    char* bufAn = sm + ((T + 1) & 1) * 32768;

    bf16x8 b00, b01, b10, b11, b20, b21, b30, b31;
    bf16x8 aA0, aA1, aA2, aA3, aB0, aB1, aB2, aB3;
    LDB8(BR);
    LDA4(aA0, aA1, aA2, aA3, bufA, 0);
    stage_half(Ag, m0, T + 1, bufAn, wave, lane);                 // A0(T+1)
    LDA4(aB0, aB1, aB2, aB3, bufA, 2);                            // pre-issue p=1
    PHASE16(aA0, aA1, aA2, aA3, 0, 1);

    stage_half(Ag, m0 + 128, T + 1, bufAn + 16384, wave, lane);   // A1(T+1)
    stage_half(Bg, n0,       T + 2, BS,            wave, lane);   // B0(T+2)
    LDA4(aA0, aA1, aA2, aA3, bufA, 4);                            // pre-issue p=2
    PHASE16(aB0, aB1, aB2, aB3, 2, 3);

    stage_half(Bg, n0 + 128, T + 2, BS + 16384, wave, lane);      // B1(T+2)
    LDA4(aB0, aB1, aB2, aB3, bufA, 6);                            // pre-issue p=3
    PHASE16(aA0, aA1, aA2, aA3, 4, 5);

    // drain A(T+1)+B(T+1) (8 oldest); keep B(T+2) (4 newest) in flight
    asm volatile("s_waitcnt vmcnt(4)" ::: "memory");
    __builtin_amdgcn_sched_barrier(0);
    PHASE16(aB0, aB1, aB2, aB3, 6, 7);
    __builtin_amdgcn_s_barrier();  // single per-tile sync

    BR = (BR == sm + B0OFF + 2 * 32768) ? sm + B0OFF : BR + 32768;
    BS = (BS == sm + B0OFF + 2 * 32768) ? sm + B0OFF : BS + 32768;
  }

  // ---- tile NT-2: stages A(NT-1) only; full drain at end
  {
    char* bufA  = sm + ((NT - 2) & 1) * 32768;
    char* bufAn = sm + ((NT - 1) & 1) * 32768;

    bf16x8 b00, b01, b10, b11, b20, b21, b30, b31;
    bf16x8 aA0, aA1, aA2, aA3, aB0, aB1, aB2, aB3;
    LDB8(BR);
    LDA4(aA0, aA1, aA2, aA3, bufA, 0);
    stage_half(Ag, m0, NT - 1, bufAn, wave, lane);
    LDA4(aB0, aB1, aB2, aB3, bufA, 2);
    PHASE16(aA0, aA1, aA2, aA3, 0, 1);

    stage_half(Ag, m0 + 128, NT - 1, bufAn + 16384, wave, lane);
    LDA4(aA0, aA1, aA2, aA3, bufA, 4);
    PHASE16(aB0, aB1, aB2, aB3, 2, 3);

    LDA4(aB0, aB1, aB2, aB3, bufA, 6);
    PHASE16(aA0, aA1, aA2, aA3, 4, 5);

    asm volatile("s_waitcnt vmcnt(0)" ::: "memory");
    __builtin_amdgcn_sched_barrier(0);
    PHASE16(aB0, aB1, aB2, aB3, 6, 7);
    __builtin_amdgcn_s_barrier();
  }

  // ---- tile NT-1: compute only (B region (NT-1)%3 == 0)
  {
    char* bufA = sm + ((NT - 1) & 1) * 32768;
    char* BR2  = sm + B0OFF;

    bf16x8 b00, b01, b10, b11, b20, b21, b30, b31;
    bf16x8 aA0, aA1, aA2, aA3, aB0, aB1, aB2, aB3;
    LDB8(BR2);
    LDA4(aA0, aA1, aA2, aA3, bufA, 0);
    LDA4(aB0, aB1, aB2, aB3, bufA, 2);
    PHASE16(aA0, aA1, aA2, aA3, 0, 1);

    LDA4(aA0, aA1, aA2, aA3, bufA, 4);
    PHASE16(aB0, aB1, aB2, aB3, 2, 3);

    LDA4(aB0, aB1, aB2, aB3, bufA, 6);
    PHASE16(aA0, aA1, aA2, aA3, 4, 5);
    PHASE16(aB0, aB1, aB2, aB3, 6, 7);
  }

  // ---- epilogue: C/D layout col=lane&15, row=(lane>>4)*4+reg ----
#pragma unroll
  for (int n = 0; n < 4; ++n) {
    const int col = n0 + wn * 64 + n * 16 + lrow;
    const float bv = bias[col];
#pragma unroll
    for (int m = 0; m < 8; ++m) {
      const int row = m0 + wm * 128 + m * 16 + khi * 4;
      float* cp = C + (size_t)row * Ndim + col;
#pragma unroll
      for (int r = 0; r < 4; ++r)
        cp[(size_t)r * Ndim] = acc[m][n][r] + bv;
    }
  }
}

// ---------------- fallback: fused fp32->bf16 GEMM (no workspace) ----------------
__global__ __launch_bounds__(256) void k_gemm_fused(const float* __restrict__ A,
                                                    const float* __restrict__ B,
                                                    const float* __restrict__ bias,
                                                    float* __restrict__ C) {
  __shared__ unsigned short lA[128 * 32];
  __shared__ unsigned short lB[32 * 136];

  const int tid = threadIdx.x;
  const int wave = tid >> 6;
  const int lane = tid & 63;
  const int lrow = lane & 15;
  const int kslc = lane >> 4;
  const int wr = wave >> 1;
  const int wc = wave & 1;

  const int bid = blockIdx.x;
  const int cpx = gridDim.x >> 3;
  const int swz = (bid & 7) * cpx + (bid >> 3);
  const int m0 = (swz & 63) * 128;
  const int n0 = (swz >> 6) * 128;

  f32x4 acc[4][4];
#pragma unroll
  for (int i = 0; i < 4; ++i)
#pragma unroll
    for (int j = 0; j < 4; ++j) acc[i][j] = f32x4{0.f, 0.f, 0.f, 0.f};

  for (int k0 = 0; k0 < Kdim; k0 += 32) {
#pragma unroll
    for (int j = 0; j < 2; ++j) {
      int e = (j * 256 + tid) * 8;
      int r = e >> 5, kk = e & 31;
      const float* src = A + (size_t)(m0 + r) * Kdim + k0 + kk;
      float4 v0 = *reinterpret_cast<const float4*>(src);
      float4 v1 = *reinterpret_cast<const float4*>(src + 4);
      u16x8 o;
      o[0] = f2bf(v0.x); o[1] = f2bf(v0.y); o[2] = f2bf(v0.z); o[3] = f2bf(v0.w);
      o[4] = f2bf(v1.x); o[5] = f2bf(v1.y); o[6] = f2bf(v1.z); o[7] = f2bf(v1.w);
      *reinterpret_cast<u16x8*>(&lA[e]) = o;
    }
#pragma unroll
    for (int j = 0; j < 2; ++j) {
      int e = (j * 256 + tid) * 8;
      int r = e >> 7, c = e & 127;
      const float* src = B + (size_t)(k0 + r) * Ndim + n0 + c;
      float4 v0 = *reinterpret_cast<const float4*>(src);
      float4 v1 = *reinterpret_cast<const float4*>(src + 4);
      u16x8 o;
      o[0] = f2bf(v0.x); o[1] = f2bf(v0.y); o[2] = f2bf(v0.z); o[3] = f2bf(v0.w);
      o[4] = f2bf(v1.x); o[5] = f2bf(v1.y); o[6] = f2bf(v1.z); o[7] = f2bf(v1.w);
      *reinterpret_cast<u16x8*>(&lB[r * 136 + c]) = o;
    }
    __syncthreads();

    bf16x8 af[4], bfv[4];
#pragma unroll
    for (int m = 0; m < 4; ++m)
      af[m] = __builtin_bit_cast(
          bf16x8, *reinterpret_cast<const u16x8*>(&lA[(wr * 64 + m * 16 + lrow) * 32 + kslc * 8]));
#pragma unroll
    for (int n = 0; n < 4; ++n) {
      union { unsigned short s[8]; u16x8 v; } t;
      int col = wc * 64 + n * 16 + lrow;
#pragma unroll
      for (int i = 0; i < 8; ++i) t.s[i] = lB[(kslc * 8 + i) * 136 + col];
      bfv[n] = __builtin_bit_cast(bf16x8, t.v);
    }

#pragma unroll
    for (int m = 0; m < 4; ++m)
#pragma unroll
      for (int n = 0; n < 4; ++n)
        acc[m][n] = __builtin_amdgcn_mfma_f32_16x16x32_bf16(af[m], bfv[n], acc[m][n], 0, 0, 0);

    __syncthreads();
  }

#pragma unroll
  for (int n = 0; n < 4; ++n) {
    const int col = n0 + wc * 64 + n * 16 + lrow;
    const float bv = bias[col];
#pragma unroll
    for (int m = 0; m < 4; ++m) {
      const int row = m0 + wr * 64 + m * 16 + kslc * 4;
      float* cp = C + (size_t)row * Ndim + col;
#pragma unroll
      for (int r = 0; r < 4; ++r)
        cp[(size_t)r * Ndim] = acc[m][n][r] + bv;
    }
  }
}

extern "C" void kernel_launch(void* const* d_in, const int* in_sizes, int n_in,
                              void* d_out, int out_size, void* d_ws, size_t ws_size,
                              hipStream_t stream) {
  const float* inp = (const float*)d_in[0];
  const float* ker = (const float*)d_in[1];
  const float* bias = (const float*)d_in[2];
  float* out = (float*)d_out;

  const size_t A_BYTES = (size_t)Mdim * Kdim * 2;  // 64 MiB
  const size_t B_BYTES = (size_t)Ndim * Kdim * 2;  // 128 MiB

  if (ws_size >= A_BYTES + B_BYTES) {
    unsigned short* Abf = (unsigned short*)d_ws;
    unsigned short* Btb = (unsigned short*)((char*)d_ws + A_BYTES);
    k_convertA<<<2048, 256, 0, stream>>>(inp, Abf, Mdim * Kdim / 8);
    dim3 tg(Ndim / 64, Kdim / 64);
    k_transB<<<tg, 256, 0, stream>>>(ker, Btb);
    (void)hipFuncSetAttribute((const void*)k_gemm8,
                              hipFuncAttributeMaxDynamicSharedMemorySize, 163840);
    const int nblocks = (Mdim / 256) * (Ndim / 256);  // 2048
    k_gemm8<<<nblocks, 512, 163840, stream>>>(Abf, Btb, bias, out);
  } else {
    const int nblocks = (Mdim / 128) * (Ndim / 128);
    k_gemm_fused<<<nblocks, 256, 0, stream>>>(inp, ker, bias, out);
  }
}

// Round 10
// 984.282 us; speedup vs baseline: 1.0956x; 1.0956x over previous
//
#include <hip/hip_runtime.h>
#include <hip/hip_bf16.h>
#include <stdint.h>

#define DI __device__ __forceinline__

typedef __attribute__((ext_vector_type(8))) __bf16 bf16x8;
typedef __attribute__((ext_vector_type(8))) unsigned short u16x8;
typedef __attribute__((ext_vector_type(4))) unsigned short u16x4;
typedef __attribute__((ext_vector_type(4))) float f32x4;

typedef __attribute__((address_space(1))) const unsigned int* gp1;
typedef __attribute__((address_space(3))) unsigned int* lp3;

static constexpr int Mdim = 8192;   // B*S
static constexpr int Kdim = 4096;   // D
static constexpr int Ndim = 16384;  // F
static constexpr int NT = Kdim / 64;     // 64 K-tiles of BK=64
static constexpr int ROWB = Kdim * 2;    // 8192 B per bf16 row (A and Bt)

// LDS map (160 KiB total, 1 block/CU):
//   A double buffer: [0, 32768), [32768, 65536)      (each 256 rows x 64 cols bf16)
//   B triple buffer: [65536, 98304), [98304, 131072), [131072, 163840)
static constexpr int B0OFF = 65536;

DI unsigned short f2bf(float f) {
  union { float f; unsigned int u; } v;
  v.f = f;
  unsigned int u = v.u;
  unsigned int r = (u + 0x7fffu + ((u >> 16) & 1u)) >> 16;  // RNE
  return (unsigned short)r;
}

DI void gload_lds16(const void* g, void* l) {
  // width=16 -> global_load_lds_dwordx4; LDS dest = wave-uniform base + lane*16
  __builtin_amdgcn_global_load_lds((gp1)g, (lp3)l, 16, 0, 0);
}

DI bf16x8 ldfrag(const char* p) {
  return __builtin_bit_cast(bf16x8, *reinterpret_cast<const u16x8*>(p));
}

#define MFMA_(A_, B_, ACC_) \
  ACC_ = __builtin_amdgcn_mfma_f32_16x16x32_bf16(A_, B_, ACC_, 0, 0, 0)

// 16-MFMA cluster: two m-rows (M0_,M1_) x 4 n-cols x K=64, setprio-wrapped
// (R9 A/B: removing setprio cost ~2% MfmaUtil — restored).
#define PHASE16(A0_, A1_, A2_, A3_, M0_, M1_)                         \
  __builtin_amdgcn_s_setprio(1);                                      \
  MFMA_(A0_, b00, acc[M0_][0]); MFMA_(A1_, b01, acc[M0_][0]);         \
  MFMA_(A2_, b00, acc[M1_][0]); MFMA_(A3_, b01, acc[M1_][0]);         \
  MFMA_(A0_, b10, acc[M0_][1]); MFMA_(A1_, b11, acc[M0_][1]);         \
  MFMA_(A2_, b10, acc[M1_][1]); MFMA_(A3_, b11, acc[M1_][1]);         \
  MFMA_(A0_, b20, acc[M0_][2]); MFMA_(A1_, b21, acc[M0_][2]);         \
  MFMA_(A2_, b20, acc[M1_][2]); MFMA_(A3_, b21, acc[M1_][2]);         \
  MFMA_(A0_, b30, acc[M0_][3]); MFMA_(A1_, b31, acc[M0_][3]);         \
  MFMA_(A2_, b30, acc[M1_][3]); MFMA_(A3_, b31, acc[M1_][3]);         \
  __builtin_amdgcn_s_setprio(0)

// load all 8 B frags of a tile from B region R_
#define LDB8(R_)                                            \
  b00 = ldfrag(R_ + boffR + 0 * 2048 + kofs0);              \
  b01 = ldfrag(R_ + boffR + 0 * 2048 + kofs1);              \
  b10 = ldfrag(R_ + boffR + 1 * 2048 + kofs0);              \
  b11 = ldfrag(R_ + boffR + 1 * 2048 + kofs1);              \
  b20 = ldfrag(R_ + boffR + 2 * 2048 + kofs0);              \
  b21 = ldfrag(R_ + boffR + 2 * 2048 + kofs1);              \
  b30 = ldfrag(R_ + boffR + 3 * 2048 + kofs0);              \
  b31 = ldfrag(R_ + boffR + 3 * 2048 + kofs1)

// load one A frag pair (rows-of-16 P_ and P_+1) from A buffer
#define LDA4(D0_, D1_, D2_, D3_, BUF_, P_)                  \
  D0_ = ldfrag(BUF_ + aoff + (P_) * 2048 + kofs0);          \
  D1_ = ldfrag(BUF_ + aoff + (P_) * 2048 + kofs1);          \
  D2_ = ldfrag(BUF_ + aoff + (P_ + 1) * 2048 + kofs0);      \
  D3_ = ldfrag(BUF_ + aoff + (P_ + 1) * 2048 + kofs1)

// Stage one 128-row x 64-col bf16 half-tile (16 KiB) into a linear LDS region.
// Global source is pre-swizzled per-lane so that a swizzled READ
// (byte ^= (row&7)<<4) sees the correct data (both-sides-or-neither rule).
DI void stage_half(const char* g, int row0, int Tk, char* region, int wave, int lane) {
  const int r = wave * 16 + (lane >> 3);
  const int colx = (((lane & 7) ^ ((lane >> 3) & 7)) << 4);
  const char* src = g + (size_t)(row0 + r) * ROWB + Tk * 128 + colx;
  char* dst = region + wave * 2048;  // wave-uniform
  gload_lds16(src, dst);
  gload_lds16(src + (size_t)8 * ROWB, dst + 1024);
}

// ---------------- pre-pass: A fp32 -> bf16 ----------------
__global__ void k_convertA(const float* __restrict__ in,
                           unsigned short* __restrict__ out, int n8) {
  int stride = gridDim.x * blockDim.x;
  for (int i = blockIdx.x * blockDim.x + threadIdx.x; i < n8; i += stride) {
    const float4* p = reinterpret_cast<const float4*>(in) + (size_t)i * 2;
    float4 a = p[0], b = p[1];
    u16x8 o;
    o[0] = f2bf(a.x); o[1] = f2bf(a.y); o[2] = f2bf(a.z); o[3] = f2bf(a.w);
    o[4] = f2bf(b.x); o[5] = f2bf(b.y); o[6] = f2bf(b.z); o[7] = f2bf(b.w);
    reinterpret_cast<u16x8*>(out)[i] = o;
  }
}

// -------- pre-pass: B (K,N) fp32 -> Bt (N,K) bf16 --------
__global__ void k_transB(const float* __restrict__ B,
                         unsigned short* __restrict__ Bt) {
  __shared__ unsigned short lds[64][68];
  const int n0 = blockIdx.x * 64;
  const int k0 = blockIdx.y * 64;
  const int tid = threadIdx.x;
  const int rr = tid >> 4;
  const int cc = tid & 15;
#pragma unroll
  for (int i = 0; i < 4; ++i) {
    int r = rr + i * 16;
    float4 v = *reinterpret_cast<const float4*>(B + (size_t)(k0 + r) * Ndim + n0 + cc * 4);
    u16x4 o;
    o[0] = f2bf(v.x); o[1] = f2bf(v.y); o[2] = f2bf(v.z); o[3] = f2bf(v.w);
    *reinterpret_cast<u16x4*>(&lds[r][cc * 4]) = o;
  }
  __syncthreads();
#pragma unroll
  for (int i = 0; i < 4; ++i) {
    int n = rr + i * 16;
    u16x4 o;
    o[0] = lds[cc * 4 + 0][n];
    o[1] = lds[cc * 4 + 1][n];
    o[2] = lds[cc * 4 + 2][n];
    o[3] = lds[cc * 4 + 3][n];
    *reinterpret_cast<u16x4*>(Bt + (size_t)(n0 + n) * Kdim + k0 + cc * 4) = o;
  }
}

// ---------------- 256x256 GEMM, 1-barrier/tile, B triple-buffered ----------------
// A(M,K) bf16 x Bt(N,K) bf16 -> C(M,N) fp32 + bias
// 512 threads = 8 waves (2M x 4N); per-wave output 128x64 of 16x16x32 MFMA.
// Block->tile map: per-XCD 8m x 4n co-resident patches (R8 order).
// Epilogue uses NON-TEMPORAL stores: avoids TCC read-for-write-allocate on C
// (512 MB of HBM fetch) and keeps A/B resident in L3.
__global__ __launch_bounds__(512, 2) void k_gemm8(const unsigned short* __restrict__ A,
                                                  const unsigned short* __restrict__ Bt,
                                                  const float* __restrict__ bias,
                                                  float* __restrict__ C) {
  extern __shared__ char sm[];
  const int tid = threadIdx.x;
  const int wave = tid >> 6, lane = tid & 63;
  const int wm = wave >> 2, wn = wave & 3;
  const int lrow = lane & 15, khi = lane >> 4;

  int m0, n0;
  {
    // 2048 blocks = 8 XCDs x 8 chunks x 32 blocks.
    // chunk c: m-slab = c>>1 (8 m-tiles), n-half = c&1 (4 n-tiles of this XCD's 8).
    const int bid = blockIdx.x;
    const int xcd = bid & 7;
    const int local = bid >> 3;      // 0..255
    const int c = local >> 5;        // 0..7
    const int i = local & 31;        // 0..31
    const int mt = (c >> 1) * 8 + (i & 7);                 // 0..31
    const int nt = xcd * 8 + (c & 1) * 4 + (i >> 3);       // 0..63
    m0 = mt * 256;
    n0 = nt * 256;
  }

  const char* Ag = (const char*)A;
  const char* Bg = (const char*)Bt;

  // swizzled within-row k-offsets for the two K=32 steps of a BK=64 tile
  const int kofs0 = (khi * 16) ^ ((lane & 7) << 4);
  const int kofs1 = (64 + khi * 16) ^ ((lane & 7) << 4);
  const int aoff  = (wm * 128 + lrow) * 128;   // A frag row base (bytes, within A buf)
  const int boffR = (wn * 64 + lrow) * 128;    // B frag row base (bytes, within B region)

  f32x4 acc[8][4];
#pragma unroll
  for (int i = 0; i < 8; ++i)
#pragma unroll
    for (int j = 0; j < 4; ++j) acc[i][j] = f32x4{0.f, 0.f, 0.f, 0.f};

  // ---- prologue: A(0), B(0), B(1); leave B(1) (4 loads) in flight
  stage_half(Ag, m0,       0, sm + 0,              wave, lane);
  stage_half(Ag, m0 + 128, 0, sm + 16384,          wave, lane);
  stage_half(Bg, n0,       0, sm + B0OFF,          wave, lane);
  stage_half(Bg, n0 + 128, 0, sm + B0OFF + 16384,  wave, lane);
  stage_half(Bg, n0,       1, sm + B0OFF + 32768,  wave, lane);
  stage_half(Bg, n0 + 128, 1, sm + B0OFF + 49152,  wave, lane);
  asm volatile("s_waitcnt vmcnt(4)" ::: "memory");
  __builtin_amdgcn_sched_barrier(0);
  __builtin_amdgcn_s_barrier();

  // rotating B region pointers: BR = read region (T%3), BS = stage region ((T+2)%3)
  char* BR = sm + B0OFF;
  char* BS = sm + B0OFF + 2 * 32768;

  // ---- steady tiles: T in [0, NT-3]; stages A(T+1), B(T+2); ONE barrier/tile
  for (int T = 0; T < NT - 2; ++T) {
    char* bufA  = sm + (T & 1) * 32768;
    char* bufAn = sm + ((T + 1) & 1) * 32768;

    bf16x8 b00, b01, b10, b11, b20, b21, b30, b31;
    bf16x8 aA0, aA1, aA2, aA3, aB0, aB1, aB2, aB3;
    LDB8(BR);
    LDA4(aA0, aA1, aA2, aA3, bufA, 0);
    stage_half(Ag, m0, T + 1, bufAn, wave, lane);                 // A0(T+1)
    LDA4(aB0, aB1, aB2, aB3, bufA, 2);                            // pre-issue p=1
    PHASE16(aA0, aA1, aA2, aA3, 0, 1);

    stage_half(Ag, m0 + 128, T + 1, bufAn + 16384, wave, lane);   // A1(T+1)
    stage_half(Bg, n0,       T + 2, BS,            wave, lane);   // B0(T+2)
    LDA4(aA0, aA1, aA2, aA3, bufA, 4);                            // pre-issue p=2
    PHASE16(aB0, aB1, aB2, aB3, 2, 3);

    stage_half(Bg, n0 + 128, T + 2, BS + 16384, wave, lane);      // B1(T+2)
    LDA4(aB0, aB1, aB2, aB3, bufA, 6);                            // pre-issue p=3
    PHASE16(aA0, aA1, aA2, aA3, 4, 5);

    // drain A(T+1)+B(T+1) (8 oldest); keep B(T+2) (4 newest) in flight
    asm volatile("s_waitcnt vmcnt(4)" ::: "memory");
    __builtin_amdgcn_sched_barrier(0);
    PHASE16(aB0, aB1, aB2, aB3, 6, 7);
    __builtin_amdgcn_s_barrier();  // single per-tile sync

    BR = (BR == sm + B0OFF + 2 * 32768) ? sm + B0OFF : BR + 32768;
    BS = (BS == sm + B0OFF + 2 * 32768) ? sm + B0OFF : BS + 32768;
  }

  // ---- tile NT-2: stages A(NT-1) only; full drain at end
  {
    char* bufA  = sm + ((NT - 2) & 1) * 32768;
    char* bufAn = sm + ((NT - 1) & 1) * 32768;

    bf16x8 b00, b01, b10, b11, b20, b21, b30, b31;
    bf16x8 aA0, aA1, aA2, aA3, aB0, aB1, aB2, aB3;
    LDB8(BR);
    LDA4(aA0, aA1, aA2, aA3, bufA, 0);
    stage_half(Ag, m0, NT - 1, bufAn, wave, lane);
    LDA4(aB0, aB1, aB2, aB3, bufA, 2);
    PHASE16(aA0, aA1, aA2, aA3, 0, 1);

    stage_half(Ag, m0 + 128, NT - 1, bufAn + 16384, wave, lane);
    LDA4(aA0, aA1, aA2, aA3, bufA, 4);
    PHASE16(aB0, aB1, aB2, aB3, 2, 3);

    LDA4(aB0, aB1, aB2, aB3, bufA, 6);
    PHASE16(aA0, aA1, aA2, aA3, 4, 5);

    asm volatile("s_waitcnt vmcnt(0)" ::: "memory");
    __builtin_amdgcn_sched_barrier(0);
    PHASE16(aB0, aB1, aB2, aB3, 6, 7);
    __builtin_amdgcn_s_barrier();
  }

  // ---- tile NT-1: compute only (B region (NT-1)%3 == 0)
  {
    char* bufA = sm + ((NT - 1) & 1) * 32768;
    char* BR2  = sm + B0OFF;

    bf16x8 b00, b01, b10, b11, b20, b21, b30, b31;
    bf16x8 aA0, aA1, aA2, aA3, aB0, aB1, aB2, aB3;
    LDB8(BR2);
    LDA4(aA0, aA1, aA2, aA3, bufA, 0);
    LDA4(aB0, aB1, aB2, aB3, bufA, 2);
    PHASE16(aA0, aA1, aA2, aA3, 0, 1);

    LDA4(aA0, aA1, aA2, aA3, bufA, 4);
    PHASE16(aB0, aB1, aB2, aB3, 2, 3);

    LDA4(aB0, aB1, aB2, aB3, bufA, 6);
    PHASE16(aA0, aA1, aA2, aA3, 4, 5);
    PHASE16(aB0, aB1, aB2, aB3, 6, 7);
  }

  // ---- epilogue: C/D layout col=lane&15, row=(lane>>4)*4+reg; NT stores ----
#pragma unroll
  for (int n = 0; n < 4; ++n) {
    const int col = n0 + wn * 64 + n * 16 + lrow;
    const float bv = bias[col];
#pragma unroll
    for (int m = 0; m < 8; ++m) {
      const int row = m0 + wm * 128 + m * 16 + khi * 4;
      float* cp = C + (size_t)row * Ndim + col;
#pragma unroll
      for (int r = 0; r < 4; ++r)
        __builtin_nontemporal_store(acc[m][n][r] + bv, cp + (size_t)r * Ndim);
    }
  }
}

// ---------------- fallback: fused fp32->bf16 GEMM (no workspace) ----------------
__global__ __launch_bounds__(256) void k_gemm_fused(const float* __restrict__ A,
                                                    const float* __restrict__ B,
                                                    const float* __restrict__ bias,
                                                    float* __restrict__ C) {
  __shared__ unsigned short lA[128 * 32];
  __shared__ unsigned short lB[32 * 136];

  const int tid = threadIdx.x;
  const int wave = tid >> 6;
  const int lane = tid & 63;
  const int lrow = lane & 15;
  const int kslc = lane >> 4;
  const int wr = wave >> 1;
  const int wc = wave & 1;

  const int bid = blockIdx.x;
  const int cpx = gridDim.x >> 3;
  const int swz = (bid & 7) * cpx + (bid >> 3);
  const int m0 = (swz & 63) * 128;
  const int n0 = (swz >> 6) * 128;

  f32x4 acc[4][4];
#pragma unroll
  for (int i = 0; i < 4; ++i)
#pragma unroll
    for (int j = 0; j < 4; ++j) acc[i][j] = f32x4{0.f, 0.f, 0.f, 0.f};

  for (int k0 = 0; k0 < Kdim; k0 += 32) {
#pragma unroll
    for (int j = 0; j < 2; ++j) {
      int e = (j * 256 + tid) * 8;
      int r = e >> 5, kk = e & 31;
      const float* src = A + (size_t)(m0 + r) * Kdim + k0 + kk;
      float4 v0 = *reinterpret_cast<const float4*>(src);
      float4 v1 = *reinterpret_cast<const float4*>(src + 4);
      u16x8 o;
      o[0] = f2bf(v0.x); o[1] = f2bf(v0.y); o[2] = f2bf(v0.z); o[3] = f2bf(v0.w);
      o[4] = f2bf(v1.x); o[5] = f2bf(v1.y); o[6] = f2bf(v1.z); o[7] = f2bf(v1.w);
      *reinterpret_cast<u16x8*>(&lA[e]) = o;
    }
#pragma unroll
    for (int j = 0; j < 2; ++j) {
      int e = (j * 256 + tid) * 8;
      int r = e >> 7, c = e & 127;
      const float* src = B + (size_t)(k0 + r) * Ndim + n0 + c;
      float4 v0 = *reinterpret_cast<const float4*>(src);
      float4 v1 = *reinterpret_cast<const float4*>(src + 4);
      u16x8 o;
      o[0] = f2bf(v0.x); o[1] = f2bf(v0.y); o[2] = f2bf(v0.z); o[3] = f2bf(v0.w);
      o[4] = f2bf(v1.x); o[5] = f2bf(v1.y); o[6] = f2bf(v1.z); o[7] = f2bf(v1.w);
      *reinterpret_cast<u16x8*>(&lB[r * 136 + c]) = o;
    }
    __syncthreads();

    bf16x8 af[4], bfv[4];
#pragma unroll
    for (int m = 0; m < 4; ++m)
      af[m] = __builtin_bit_cast(
          bf16x8, *reinterpret_cast<const u16x8*>(&lA[(wr * 64 + m * 16 + lrow) * 32 + kslc * 8]));
#pragma unroll
    for (int n = 0; n < 4; ++n) {
      union { unsigned short s[8]; u16x8 v; } t;
      int col = wc * 64 + n * 16 + lrow;
#pragma unroll
      for (int i = 0; i < 8; ++i) t.s[i] = lB[(kslc * 8 + i) * 136 + col];
      bfv[n] = __builtin_bit_cast(bf16x8, t.v);
    }

#pragma unroll
    for (int m = 0; m < 4; ++m)
#pragma unroll
      for (int n = 0; n < 4; ++n)
        acc[m][n] = __builtin_amdgcn_mfma_f32_16x16x32_bf16(af[m], bfv[n], acc[m][n], 0, 0, 0);

    __syncthreads();
  }

#pragma unroll
  for (int n = 0; n < 4; ++n) {
    const int col = n0 + wc * 64 + n * 16 + lrow;
    const float bv = bias[col];
#pragma unroll
    for (int m = 0; m < 4; ++m) {
      const int row = m0 + wr * 64 + m * 16 + kslc * 4;
      float* cp = C + (size_t)row * Ndim + col;
#pragma unroll
      for (int r = 0; r < 4; ++r)
        cp[(size_t)r * Ndim] = acc[m][n][r] + bv;
    }
  }
}

extern "C" void kernel_launch(void* const* d_in, const int* in_sizes, int n_in,
                              void* d_out, int out_size, void* d_ws, size_t ws_size,
                              hipStream_t stream) {
  const float* inp = (const float*)d_in[0];
  const float* ker = (const float*)d_in[1];
  const float* bias = (const float*)d_in[2];
  float* out = (float*)d_out;

  const size_t A_BYTES = (size_t)Mdim * Kdim * 2;  // 64 MiB
  const size_t B_BYTES = (size_t)Ndim * Kdim * 2;  // 128 MiB

  if (ws_size >= A_BYTES + B_BYTES) {
    unsigned short* Abf = (unsigned short*)d_ws;
    unsigned short* Btb = (unsigned short*)((char*)d_ws + A_BYTES);
    k_convertA<<<2048, 256, 0, stream>>>(inp, Abf, Mdim * Kdim / 8);
    dim3 tg(Ndim / 64, Kdim / 64);
    k_transB<<<tg, 256, 0, stream>>>(ker, Btb);
    (void)hipFuncSetAttribute((const void*)k_gemm8,
                              hipFuncAttributeMaxDynamicSharedMemorySize, 163840);
    const int nblocks = (Mdim / 256) * (Ndim / 256);  // 2048
    k_gemm8<<<nblocks, 512, 163840, stream>>>(Abf, Btb, bias, out);
  } else {
    const int nblocks = (Mdim / 128) * (Ndim / 128);
    k_gemm_fused<<<nblocks, 256, 0, stream>>>(inp, ker, bias, out);
  }
}

// Round 11
// 952.453 us; speedup vs baseline: 1.1322x; 1.0334x over previous
//
#include <hip/hip_runtime.h>
#include <hip/hip_bf16.h>
#include <stdint.h>

#define DI __device__ __forceinline__

typedef __attribute__((ext_vector_type(8))) __bf16 bf16x8;
typedef __attribute__((ext_vector_type(8))) unsigned short u16x8;
typedef __attribute__((ext_vector_type(4))) unsigned short u16x4;
typedef __attribute__((ext_vector_type(4))) float f32x4;

typedef __attribute__((address_space(1))) const unsigned int* gp1;
typedef __attribute__((address_space(3))) unsigned int* lp3;

static constexpr int Mdim = 8192;   // B*S
static constexpr int Kdim = 4096;   // D
static constexpr int Ndim = 16384;  // F
static constexpr int NT = Kdim / 64;     // 64 K-tiles of BK=64
static constexpr int ROWB = Kdim * 2;    // 8192 B per bf16 row (A and Bt)

// LDS map (160 KiB total, 1 block/CU):
//   A double buffer: [0, 32768), [32768, 65536)
//   B triple buffer: [65536, 98304), [98304, 131072), [131072, 163840)
//   epilogue scratch reuses [98304, 133120) after the K-loop (regions 1-2 dead)
static constexpr int B0OFF = 65536;
static constexpr int EOFF  = 98304;

DI unsigned short f2bf(float f) {
  union { float f; unsigned int u; } v;
  v.f = f;
  unsigned int u = v.u;
  unsigned int r = (u + 0x7fffu + ((u >> 16) & 1u)) >> 16;  // RNE
  return (unsigned short)r;
}

DI void gload_lds16(const void* g, void* l) {
  // width=16 -> global_load_lds_dwordx4; LDS dest = wave-uniform base + lane*16
  __builtin_amdgcn_global_load_lds((gp1)g, (lp3)l, 16, 0, 0);
}

DI bf16x8 ldfrag(const char* p) {
  return __builtin_bit_cast(bf16x8, *reinterpret_cast<const u16x8*>(p));
}

#define MFMA_(A_, B_, ACC_) \
  ACC_ = __builtin_amdgcn_mfma_f32_16x16x32_bf16(A_, B_, ACC_, 0, 0, 0)

// 16-MFMA cluster: two m-rows (M0_,M1_) x 4 n-cols x K=64, setprio-wrapped
// (R9 A/B: removing setprio cost ~2% MfmaUtil — kept).
#define PHASE16(A0_, A1_, A2_, A3_, M0_, M1_)                         \
  __builtin_amdgcn_s_setprio(1);                                      \
  MFMA_(A0_, b00, acc[M0_][0]); MFMA_(A1_, b01, acc[M0_][0]);         \
  MFMA_(A2_, b00, acc[M1_][0]); MFMA_(A3_, b01, acc[M1_][0]);         \
  MFMA_(A0_, b10, acc[M0_][1]); MFMA_(A1_, b11, acc[M0_][1]);         \
  MFMA_(A2_, b10, acc[M1_][1]); MFMA_(A3_, b11, acc[M1_][1]);         \
  MFMA_(A0_, b20, acc[M0_][2]); MFMA_(A1_, b21, acc[M0_][2]);         \
  MFMA_(A2_, b20, acc[M1_][2]); MFMA_(A3_, b21, acc[M1_][2]);         \
  MFMA_(A0_, b30, acc[M0_][3]); MFMA_(A1_, b31, acc[M0_][3]);         \
  MFMA_(A2_, b30, acc[M1_][3]); MFMA_(A3_, b31, acc[M1_][3]);         \
  __builtin_amdgcn_s_setprio(0)

// load all 8 B frags of a tile from B region R_
#define LDB8(R_)                                            \
  b00 = ldfrag(R_ + boffR + 0 * 2048 + kofs0);              \
  b01 = ldfrag(R_ + boffR + 0 * 2048 + kofs1);              \
  b10 = ldfrag(R_ + boffR + 1 * 2048 + kofs0);              \
  b11 = ldfrag(R_ + boffR + 1 * 2048 + kofs1);              \
  b20 = ldfrag(R_ + boffR + 2 * 2048 + kofs0);              \
  b21 = ldfrag(R_ + boffR + 2 * 2048 + kofs1);              \
  b30 = ldfrag(R_ + boffR + 3 * 2048 + kofs0);              \
  b31 = ldfrag(R_ + boffR + 3 * 2048 + kofs1)

// load one A frag pair (rows-of-16 P_ and P_+1) from A buffer
#define LDA4(D0_, D1_, D2_, D3_, BUF_, P_)                  \
  D0_ = ldfrag(BUF_ + aoff + (P_) * 2048 + kofs0);          \
  D1_ = ldfrag(BUF_ + aoff + (P_) * 2048 + kofs1);          \
  D2_ = ldfrag(BUF_ + aoff + (P_ + 1) * 2048 + kofs0);      \
  D3_ = ldfrag(BUF_ + aoff + (P_ + 1) * 2048 + kofs1)

// Stage one 128-row x 64-col bf16 half-tile (16 KiB) into a linear LDS region.
// Global source is pre-swizzled per-lane so that a swizzled READ
// (byte ^= (row&7)<<4) sees the correct data (both-sides-or-neither rule).
DI void stage_half(const char* g, int row0, int Tk, char* region, int wave, int lane) {
  const int r = wave * 16 + (lane >> 3);
  const int colx = (((lane & 7) ^ ((lane >> 3) & 7)) << 4);
  const char* src = g + (size_t)(row0 + r) * ROWB + Tk * 128 + colx;
  char* dst = region + wave * 2048;  // wave-uniform
  gload_lds16(src, dst);
  gload_lds16(src + (size_t)8 * ROWB, dst + 1024);
}

// ---------------- pre-pass: A fp32 -> bf16 ----------------
__global__ void k_convertA(const float* __restrict__ in,
                           unsigned short* __restrict__ out, int n8) {
  int stride = gridDim.x * blockDim.x;
  for (int i = blockIdx.x * blockDim.x + threadIdx.x; i < n8; i += stride) {
    const float4* p = reinterpret_cast<const float4*>(in) + (size_t)i * 2;
    float4 a = p[0], b = p[1];
    u16x8 o;
    o[0] = f2bf(a.x); o[1] = f2bf(a.y); o[2] = f2bf(a.z); o[3] = f2bf(a.w);
    o[4] = f2bf(b.x); o[5] = f2bf(b.y); o[6] = f2bf(b.z); o[7] = f2bf(b.w);
    reinterpret_cast<u16x8*>(out)[i] = o;
  }
}

// -------- pre-pass: B (K,N) fp32 -> Bt (N,K) bf16 --------
__global__ void k_transB(const float* __restrict__ B,
                         unsigned short* __restrict__ Bt) {
  __shared__ unsigned short lds[64][68];
  const int n0 = blockIdx.x * 64;
  const int k0 = blockIdx.y * 64;
  const int tid = threadIdx.x;
  const int rr = tid >> 4;
  const int cc = tid & 15;
#pragma unroll
  for (int i = 0; i < 4; ++i) {
    int r = rr + i * 16;
    float4 v = *reinterpret_cast<const float4*>(B + (size_t)(k0 + r) * Ndim + n0 + cc * 4);
    u16x4 o;
    o[0] = f2bf(v.x); o[1] = f2bf(v.y); o[2] = f2bf(v.z); o[3] = f2bf(v.w);
    *reinterpret_cast<u16x4*>(&lds[r][cc * 4]) = o;
  }
  __syncthreads();
#pragma unroll
  for (int i = 0; i < 4; ++i) {
    int n = rr + i * 16;
    u16x4 o;
    o[0] = lds[cc * 4 + 0][n];
    o[1] = lds[cc * 4 + 1][n];
    o[2] = lds[cc * 4 + 2][n];
    o[3] = lds[cc * 4 + 3][n];
    *reinterpret_cast<u16x4*>(Bt + (size_t)(n0 + n) * Kdim + k0 + cc * 4) = o;
  }
}

// ---------------- 256x256 GEMM, 1-barrier/tile, B triple-buffered ----------------
// A(M,K) bf16 x Bt(N,K) bf16 -> C(M,N) fp32 + bias
// 512 threads = 8 waves (2M x 4N); per-wave output 128x64 of 16x16x32 MFMA.
// Epilogue: LDS-transpose -> full-line global_store_dwordx4 nt (no RFO fetch).
__global__ __launch_bounds__(512, 2) void k_gemm8(const unsigned short* __restrict__ A,
                                                  const unsigned short* __restrict__ Bt,
                                                  const float* __restrict__ bias,
                                                  float* __restrict__ C) {
  extern __shared__ char sm[];
  const int tid = threadIdx.x;
  const int wave = tid >> 6, lane = tid & 63;
  const int wm = wave >> 2, wn = wave & 3;
  const int lrow = lane & 15, khi = lane >> 4;

  int m0, n0;
  {
    // 2048 blocks = 8 XCDs x 8 chunks x 32 blocks (R8 map).
    const int bid = blockIdx.x;
    const int xcd = bid & 7;
    const int local = bid >> 3;      // 0..255
    const int c = local >> 5;        // 0..7
    const int i = local & 31;        // 0..31
    const int mt = (c >> 1) * 8 + (i & 7);                 // 0..31
    const int nt = xcd * 8 + (c & 1) * 4 + (i >> 3);       // 0..63
    m0 = mt * 256;
    n0 = nt * 256;
  }

  const char* Ag = (const char*)A;
  const char* Bg = (const char*)Bt;

  // swizzled within-row k-offsets for the two K=32 steps of a BK=64 tile
  const int kofs0 = (khi * 16) ^ ((lane & 7) << 4);
  const int kofs1 = (64 + khi * 16) ^ ((lane & 7) << 4);
  const int aoff  = (wm * 128 + lrow) * 128;   // A frag row base (bytes, within A buf)
  const int boffR = (wn * 64 + lrow) * 128;    // B frag row base (bytes, within B region)

  f32x4 acc[8][4];
#pragma unroll
  for (int i = 0; i < 8; ++i)
#pragma unroll
    for (int j = 0; j < 4; ++j) acc[i][j] = f32x4{0.f, 0.f, 0.f, 0.f};

  // ---- prologue: A(0), B(0), B(1); leave B(1) (4 loads) in flight
  stage_half(Ag, m0,       0, sm + 0,              wave, lane);
  stage_half(Ag, m0 + 128, 0, sm + 16384,          wave, lane);
  stage_half(Bg, n0,       0, sm + B0OFF,          wave, lane);
  stage_half(Bg, n0 + 128, 0, sm + B0OFF + 16384,  wave, lane);
  stage_half(Bg, n0,       1, sm + B0OFF + 32768,  wave, lane);
  stage_half(Bg, n0 + 128, 1, sm + B0OFF + 49152,  wave, lane);
  asm volatile("s_waitcnt vmcnt(4)" ::: "memory");
  __builtin_amdgcn_sched_barrier(0);
  __builtin_amdgcn_s_barrier();

  // rotating B region pointers: BR = read region (T%3), BS = stage region ((T+2)%3)
  char* BR = sm + B0OFF;
  char* BS = sm + B0OFF + 2 * 32768;

  // ---- steady tiles: T in [0, NT-3]; stages A(T+1), B(T+2); ONE barrier/tile
  for (int T = 0; T < NT - 2; ++T) {
    char* bufA  = sm + (T & 1) * 32768;
    char* bufAn = sm + ((T + 1) & 1) * 32768;

    bf16x8 b00, b01, b10, b11, b20, b21, b30, b31;
    bf16x8 aA0, aA1, aA2, aA3, aB0, aB1, aB2, aB3;
    LDB8(BR);
    LDA4(aA0, aA1, aA2, aA3, bufA, 0);
    stage_half(Ag, m0, T + 1, bufAn, wave, lane);                 // A0(T+1)
    LDA4(aB0, aB1, aB2, aB3, bufA, 2);                            // pre-issue p=1
    PHASE16(aA0, aA1, aA2, aA3, 0, 1);

    stage_half(Ag, m0 + 128, T + 1, bufAn + 16384, wave, lane);   // A1(T+1)
    stage_half(Bg, n0,       T + 2, BS,            wave, lane);   // B0(T+2)
    LDA4(aA0, aA1, aA2, aA3, bufA, 4);                            // pre-issue p=2
    PHASE16(aB0, aB1, aB2, aB3, 2, 3);

    stage_half(Bg, n0 + 128, T + 2, BS + 16384, wave, lane);      // B1(T+2)
    LDA4(aB0, aB1, aB2, aB3, bufA, 6);                            // pre-issue p=3
    PHASE16(aA0, aA1, aA2, aA3, 4, 5);

    // drain A(T+1)+B(T+1) (8 oldest); keep B(T+2) (4 newest) in flight
    asm volatile("s_waitcnt vmcnt(4)" ::: "memory");
    __builtin_amdgcn_sched_barrier(0);
    PHASE16(aB0, aB1, aB2, aB3, 6, 7);
    __builtin_amdgcn_s_barrier();  // single per-tile sync

    BR = (BR == sm + B0OFF + 2 * 32768) ? sm + B0OFF : BR + 32768;
    BS = (BS == sm + B0OFF + 2 * 32768) ? sm + B0OFF : BS + 32768;
  }

  // ---- tile NT-2: stages A(NT-1) only; full drain at end
  {
    char* bufA  = sm + ((NT - 2) & 1) * 32768;
    char* bufAn = sm + ((NT - 1) & 1) * 32768;

    bf16x8 b00, b01, b10, b11, b20, b21, b30, b31;
    bf16x8 aA0, aA1, aA2, aA3, aB0, aB1, aB2, aB3;
    LDB8(BR);
    LDA4(aA0, aA1, aA2, aA3, bufA, 0);
    stage_half(Ag, m0, NT - 1, bufAn, wave, lane);
    LDA4(aB0, aB1, aB2, aB3, bufA, 2);
    PHASE16(aA0, aA1, aA2, aA3, 0, 1);

    stage_half(Ag, m0 + 128, NT - 1, bufAn + 16384, wave, lane);
    LDA4(aA0, aA1, aA2, aA3, bufA, 4);
    PHASE16(aB0, aB1, aB2, aB3, 2, 3);

    LDA4(aB0, aB1, aB2, aB3, bufA, 6);
    PHASE16(aA0, aA1, aA2, aA3, 4, 5);

    asm volatile("s_waitcnt vmcnt(0)" ::: "memory");
    __builtin_amdgcn_sched_barrier(0);
    PHASE16(aB0, aB1, aB2, aB3, 6, 7);
    __builtin_amdgcn_s_barrier();
  }

  // ---- tile NT-1: compute only (B region (NT-1)%3 == 0)
  {
    char* bufA = sm + ((NT - 1) & 1) * 32768;
    char* BR2  = sm + B0OFF;

    bf16x8 b00, b01, b10, b11, b20, b21, b30, b31;
    bf16x8 aA0, aA1, aA2, aA3, aB0, aB1, aB2, aB3;
    LDB8(BR2);
    LDA4(aA0, aA1, aA2, aA3, bufA, 0);
    LDA4(aB0, aB1, aB2, aB3, bufA, 2);
    PHASE16(aA0, aA1, aA2, aA3, 0, 1);

    LDA4(aA0, aA1, aA2, aA3, bufA, 4);
    PHASE16(aB0, aB1, aB2, aB3, 2, 3);

    LDA4(aB0, aB1, aB2, aB3, bufA, 6);
    PHASE16(aA0, aA1, aA2, aA3, 4, 5);
    PHASE16(aB0, aB1, aB2, aB3, 6, 7);
  }

  // ---- epilogue v2: per-wave LDS transpose -> full-line dwordx4 NT stores ----
  // Region [EOFF, EOFF+8*4352) is dead after the K-loop (B regions 1-2; last
  // tile reads only region 0 and bufA@32768; all gload_lds drained). Private
  // per wave -> no barrier needed. Layout: [16 rows][68 floats] (pad breaks
  // the 4-way write alias; row base stays 16B-aligned for ds_read_b128).
  {
    float* ep = reinterpret_cast<float*>(sm + EOFF) + wave * 1088;  // 16*68
    const f32x4 bias4 =
        *reinterpret_cast<const f32x4*>(bias + n0 + wn * 64 + (lane & 15) * 4);
#pragma unroll
    for (int m = 0; m < 8; ++m) {
#pragma unroll
      for (int n = 0; n < 4; ++n) {
        const int col = n * 16 + lrow;
#pragma unroll
        for (int r = 0; r < 4; ++r)
          ep[(khi * 4 + r) * 68 + col] = acc[m][n][r];
      }
#pragma unroll
      for (int j = 0; j < 4; ++j) {
        const int row = j * 4 + khi;          // lane>>4 spreads 4 rows
        const int c4 = (lane & 15) * 4;       // 16 lanes -> 64 contiguous cols
        f32x4 v = *reinterpret_cast<const f32x4*>(&ep[row * 68 + c4]);
        v = v + bias4;
        const int grow = m0 + wm * 128 + m * 16 + row;
        float* gp = C + (size_t)grow * Ndim + n0 + wn * 64 + c4;
        __builtin_nontemporal_store(v, reinterpret_cast<f32x4*>(gp));
      }
      __builtin_amdgcn_sched_barrier(0);  // keep next m's writes after reads
    }
  }
}

// ---------------- fallback: fused fp32->bf16 GEMM (no workspace) ----------------
__global__ __launch_bounds__(256) void k_gemm_fused(const float* __restrict__ A,
                                                    const float* __restrict__ B,
                                                    const float* __restrict__ bias,
                                                    float* __restrict__ C) {
  __shared__ unsigned short lA[128 * 32];
  __shared__ unsigned short lB[32 * 136];

  const int tid = threadIdx.x;
  const int wave = tid >> 6;
  const int lane = tid & 63;
  const int lrow = lane & 15;
  const int kslc = lane >> 4;
  const int wr = wave >> 1;
  const int wc = wave & 1;

  const int bid = blockIdx.x;
  const int cpx = gridDim.x >> 3;
  const int swz = (bid & 7) * cpx + (bid >> 3);
  const int m0 = (swz & 63) * 128;
  const int n0 = (swz >> 6) * 128;

  f32x4 acc[4][4];
#pragma unroll
  for (int i = 0; i < 4; ++i)
#pragma unroll
    for (int j = 0; j < 4; ++j) acc[i][j] = f32x4{0.f, 0.f, 0.f, 0.f};

  for (int k0 = 0; k0 < Kdim; k0 += 32) {
#pragma unroll
    for (int j = 0; j < 2; ++j) {
      int e = (j * 256 + tid) * 8;
      int r = e >> 5, kk = e & 31;
      const float* src = A + (size_t)(m0 + r) * Kdim + k0 + kk;
      float4 v0 = *reinterpret_cast<const float4*>(src);
      float4 v1 = *reinterpret_cast<const float4*>(src + 4);
      u16x8 o;
      o[0] = f2bf(v0.x); o[1] = f2bf(v0.y); o[2] = f2bf(v0.z); o[3] = f2bf(v0.w);
      o[4] = f2bf(v1.x); o[5] = f2bf(v1.y); o[6] = f2bf(v1.z); o[7] = f2bf(v1.w);
      *reinterpret_cast<u16x8*>(&lA[e]) = o;
    }
#pragma unroll
    for (int j = 0; j < 2; ++j) {
      int e = (j * 256 + tid) * 8;
      int r = e >> 7, c = e & 127;
      const float* src = B + (size_t)(k0 + r) * Ndim + n0 + c;
      float4 v0 = *reinterpret_cast<const float4*>(src);
      float4 v1 = *reinterpret_cast<const float4*>(src + 4);
      u16x8 o;
      o[0] = f2bf(v0.x); o[1] = f2bf(v0.y); o[2] = f2bf(v0.z); o[3] = f2bf(v0.w);
      o[4] = f2bf(v1.x); o[5] = f2bf(v1.y); o[6] = f2bf(v1.z); o[7] = f2bf(v1.w);
      *reinterpret_cast<u16x8*>(&lB[r * 136 + c]) = o;
    }
    __syncthreads();

    bf16x8 af[4], bfv[4];
#pragma unroll
    for (int m = 0; m < 4; ++m)
      af[m] = __builtin_bit_cast(
          bf16x8, *reinterpret_cast<const u16x8*>(&lA[(wr * 64 + m * 16 + lrow) * 32 + kslc * 8]));
#pragma unroll
    for (int n = 0; n < 4; ++n) {
      union { unsigned short s[8]; u16x8 v; } t;
      int col = wc * 64 + n * 16 + lrow;
#pragma unroll
      for (int i = 0; i < 8; ++i) t.s[i] = lB[(kslc * 8 + i) * 136 + col];
      bfv[n] = __builtin_bit_cast(bf16x8, t.v);
    }

#pragma unroll
    for (int m = 0; m < 4; ++m)
#pragma unroll
      for (int n = 0; n < 4; ++n)
        acc[m][n] = __builtin_amdgcn_mfma_f32_16x16x32_bf16(af[m], bfv[n], acc[m][n], 0, 0, 0);

    __syncthreads();
  }

#pragma unroll
  for (int n = 0; n < 4; ++n) {
    const int col = n0 + wc * 64 + n * 16 + lrow;
    const float bv = bias[col];
#pragma unroll
    for (int m = 0; m < 4; ++m) {
      const int row = m0 + wr * 64 + m * 16 + kslc * 4;
      float* cp = C + (size_t)row * Ndim + col;
#pragma unroll
      for (int r = 0; r < 4; ++r)
        cp[(size_t)r * Ndim] = acc[m][n][r] + bv;
    }
  }
}

extern "C" void kernel_launch(void* const* d_in, const int* in_sizes, int n_in,
                              void* d_out, int out_size, void* d_ws, size_t ws_size,
                              hipStream_t stream) {
  const float* inp = (const float*)d_in[0];
  const float* ker = (const float*)d_in[1];
  const float* bias = (const float*)d_in[2];
  float* out = (float*)d_out;

  const size_t A_BYTES = (size_t)Mdim * Kdim * 2;  // 64 MiB
  const size_t B_BYTES = (size_t)Ndim * Kdim * 2;  // 128 MiB

  if (ws_size >= A_BYTES + B_BYTES) {
    unsigned short* Abf = (unsigned short*)d_ws;
    unsigned short* Btb = (unsigned short*)((char*)d_ws + A_BYTES);
    k_convertA<<<2048, 256, 0, stream>>>(inp, Abf, Mdim * Kdim / 8);
    dim3 tg(Ndim / 64, Kdim / 64);
    k_transB<<<tg, 256, 0, stream>>>(ker, Btb);
    (void)hipFuncSetAttribute((const void*)k_gemm8,
                              hipFuncAttributeMaxDynamicSharedMemorySize, 163840);
    const int nblocks = (Mdim / 256) * (Ndim / 256);  // 2048
    k_gemm8<<<nblocks, 512, 163840, stream>>>(Abf, Btb, bias, out);
  } else {
    const int nblocks = (Mdim / 128) * (Ndim / 128);
    k_gemm_fused<<<nblocks, 256, 0, stream>>>(inp, ker, bias, out);
  }
}